// Round 6
// baseline (1590.938 us; speedup 1.0000x reference)
//
#include <hip/hip_runtime.h>
#include <hip/hip_bf16.h>
#include <stdint.h>

#define DEPTH 6
#define DM 1024
#define DFF 4096
#define NH 16
#define DH 64
#define BATCH 4
#define SEQ 1024
#define NTOK (BATCH*SEQ)
#define QKVLD 3072

using bf16x8 = __attribute__((ext_vector_type(8))) short;
using f32x4  = __attribute__((ext_vector_type(4))) float;
typedef unsigned short u16;

__device__ __forceinline__ u16 f2bf(float f) {
  union { float f; uint32_t u; } v; v.f = f;
  return (u16)((v.u + 0x7FFFu + ((v.u >> 16) & 1u)) >> 16);
}

// async global->LDS, 16B per lane. LDS dest must be wave-uniform base + lane*16.
__device__ __forceinline__ void async16(void* lds, const void* g) {
  __builtin_amdgcn_global_load_lds(
      (__attribute__((address_space(1))) void*)(unsigned long long)g,
      (__attribute__((address_space(3))) void*)(unsigned int)(unsigned long long)lds,
      16, 0, 0);
}

// raw barrier + compile-time fence (prevents LDS reads hoisting above it;
// vmcnt/lgkm discipline is handled manually — do NOT use __syncthreads in the
// pipelined kernel, it drains vmcnt(0) and kills the prefetch)
#define BARRIER() do { __builtin_amdgcn_s_barrier(); asm volatile("" ::: "memory"); } while (0)

// ---------------------------------------------------------------------------
// prep: ALL weight conversions for one layer in ONE dispatch.
// ---------------------------------------------------------------------------
__global__ __launch_bounds__(256)
void prep(const float* __restrict__ wq, const float* __restrict__ wk,
          const float* __restrict__ wv, const float* __restrict__ wo,
          const float* __restrict__ w1, const float* __restrict__ w2,
          const float* __restrict__ bq, const float* __restrict__ bk,
          const float* __restrict__ bv,
          u16* __restrict__ wqkvT, u16* __restrict__ woT,
          u16* __restrict__ w1T, u16* __restrict__ w2T,
          float* __restrict__ bqkv) {
  const int bid = blockIdx.x;
  if (bid >= 12288) {
    const int t = (bid - 12288) * 256 + threadIdx.x;  // 0..3071
    bqkv[t] = t < 1024 ? bq[t] : (t < 2048 ? bk[t - 1024] : bv[t - 2048]);
    return;
  }
  const float* w; u16* wt; int K, N, tile;
  if (bid < 3072)      { const int r = bid >> 10;
                         w = r == 0 ? wq : (r == 1 ? wk : wv);
                         wt = wqkvT + (size_t)r * 1024 * 1024; K = 1024; N = 1024; tile = bid & 1023; }
  else if (bid < 4096) { w = wo; wt = woT; K = 1024; N = 1024; tile = bid - 3072; }
  else if (bid < 8192) { w = w1; wt = w1T; K = 1024; N = 4096; tile = bid - 4096; }
  else                 { w = w2; wt = w2T; K = 4096; N = 1024; tile = bid - 8192; }
  const int ntn = N >> 5;
  const int k0 = (tile / ntn) << 5, n0 = (tile % ntn) << 5;

  __shared__ u16 t[32][33];
  const int tx = threadIdx.x & 31, ty = threadIdx.x >> 5;
  #pragma unroll
  for (int r = ty; r < 32; r += 8)
    t[r][tx] = f2bf(w[(size_t)(k0 + r) * N + n0 + tx]);
  __syncthreads();
  #pragma unroll
  for (int r = ty; r < 32; r += 8)
    wt[(size_t)(n0 + r) * K + k0 + tx] = t[tx][r];
}

// ---------------------------------------------------------------------------
// V-transpose: qkv[tok][3072] section 2048.. -> vt[(b*1024+hd)][s]  (bf16)
// ---------------------------------------------------------------------------
__global__ __launch_bounds__(256)
void vtrans(const u16* __restrict__ qkv, u16* __restrict__ vt) {
  __shared__ u16 t[64][72];
  const int s0 = blockIdx.x * 64, c0 = blockIdx.y * 64, b = blockIdx.z;
  const int r = threadIdx.x >> 2, cq = threadIdx.x & 3;
  const u16* src = qkv + ((size_t)(b * SEQ + s0 + r)) * QKVLD + 2048 + c0 + cq * 16;
  *(bf16x8*)&t[r][cq * 16]     = *(const bf16x8*)(src);
  *(bf16x8*)&t[r][cq * 16 + 8] = *(const bf16x8*)(src + 8);
  __syncthreads();
  bf16x8 a, bvec;
  #pragma unroll
  for (int i = 0; i < 8; i++) a[i] = (short)t[cq * 16 + i][r];
  #pragma unroll
  for (int i = 0; i < 8; i++) bvec[i] = (short)t[cq * 16 + 8 + i][r];
  u16* dst = vt + ((size_t)(b * 1024 + c0 + r)) * SEQ + s0 + cq * 16;
  *(bf16x8*)dst = a;
  *(bf16x8*)(dst + 8) = bvec;
}

// ---------------------------------------------------------------------------
// Mask all-ones flags (per batch)
// ---------------------------------------------------------------------------
__global__ void flags_init(int* flags) {
  if (threadIdx.x < BATCH) flags[threadIdx.x] = 1;
}
__global__ void mask_flags(const int* __restrict__ mask, int* __restrict__ flags) {
  const size_t n = (size_t)BATCH * SEQ * SEQ;
  for (size_t i = (size_t)blockIdx.x * 256 + threadIdx.x; i < n; i += (size_t)gridDim.x * 256)
    if (mask[i] == 0) flags[i / ((size_t)SEQ * SEQ)] = 0;
}

// ---------------------------------------------------------------------------
// Dual LayerNorm: x f32 -> o1,o2 bf16
// ---------------------------------------------------------------------------
__global__ __launch_bounds__(256)
void ln_dual(const float* __restrict__ x,
             const float* __restrict__ g1, const float* __restrict__ b1v,
             const float* __restrict__ g2, const float* __restrict__ b2v,
             u16* __restrict__ o1, u16* __restrict__ o2) {
  const int row = blockIdx.x, tid = threadIdx.x;
  const float4 v = ((const float4*)(x + (size_t)row * DM))[tid];
  float s = v.x + v.y + v.z + v.w;
  float sq = v.x*v.x + v.y*v.y + v.z*v.z + v.w*v.w;
  #pragma unroll
  for (int o = 32; o; o >>= 1) { s += __shfl_xor(s, o); sq += __shfl_xor(sq, o); }
  __shared__ float red[8];
  const int lane = tid & 63, w = tid >> 6;
  if (lane == 0) { red[w] = s; red[4 + w] = sq; }
  __syncthreads();
  s = red[0] + red[1] + red[2] + red[3];
  sq = red[4] + red[5] + red[6] + red[7];
  const float mean = s * (1.0f / DM);
  const float rinv = rsqrtf(sq * (1.0f / DM) - mean * mean + 1e-5f);
  const float4 G1 = ((const float4*)g1)[tid], B1 = ((const float4*)b1v)[tid];
  const float4 G2 = ((const float4*)g2)[tid], B2 = ((const float4*)b2v)[tid];
  const float n0 = (v.x - mean) * rinv, n1 = (v.y - mean) * rinv;
  const float n2 = (v.z - mean) * rinv, n3 = (v.w - mean) * rinv;
  ushort4 a, bb;
  a.x = f2bf(n0*G1.x + B1.x); a.y = f2bf(n1*G1.y + B1.y);
  a.z = f2bf(n2*G1.z + B1.z); a.w = f2bf(n3*G1.w + B1.w);
  bb.x = f2bf(n0*G2.x + B2.x); bb.y = f2bf(n1*G2.y + B2.y);
  bb.z = f2bf(n2*G2.z + B2.z); bb.w = f2bf(n3*G2.w + B2.w);
  ((ushort4*)(o1 + (size_t)row * DM))[tid] = a;
  ((ushort4*)(o2 + (size_t)row * DM))[tid] = bb;
}

__global__ __launch_bounds__(256)
void ln_final(const float* __restrict__ x, const float* __restrict__ g,
              const float* __restrict__ b, float* __restrict__ out) {
  const int row = blockIdx.x, tid = threadIdx.x;
  const float4 v = ((const float4*)(x + (size_t)row * DM))[tid];
  float s = v.x + v.y + v.z + v.w;
  float sq = v.x*v.x + v.y*v.y + v.z*v.z + v.w*v.w;
  #pragma unroll
  for (int o = 32; o; o >>= 1) { s += __shfl_xor(s, o); sq += __shfl_xor(sq, o); }
  __shared__ float red[8];
  const int lane = tid & 63, w = tid >> 6;
  if (lane == 0) { red[w] = s; red[4 + w] = sq; }
  __syncthreads();
  s = red[0] + red[1] + red[2] + red[3];
  sq = red[4] + red[5] + red[6] + red[7];
  const float mean = s * (1.0f / DM);
  const float rinv = rsqrtf(sq * (1.0f / DM) - mean * mean + 1e-5f);
  const float4 G = ((const float4*)g)[tid], B = ((const float4*)b)[tid];
  float4 o;
  o.x = (v.x - mean) * rinv * G.x + B.x;
  o.y = (v.y - mean) * rinv * G.y + B.y;
  o.z = (v.z - mean) * rinv * G.z + B.z;
  o.w = (v.w - mean) * rinv * G.w + B.w;
  ((float4*)(out + (size_t)row * DM))[tid] = o;
}

// ---------------------------------------------------------------------------
// gemm256: 256x256 tile, BK=64, 8 waves (2M x 4N), per-wave 128x64 output.
// Deep pipeline: K-tile double buffer, 4 quadrant-phases/K-tile, stage issues
// at p2 (B) / p3 (A) into the buffer whose last read was >=1 barrier earlier,
// counted vmcnt(8) gate at K-tile boundary (loads stay in flight ~5 phases).
// LDS XOR swizzle byte ^= ((byte>>7)&7)<<4 via pre-swizzled global source.
// EPI: 0 bias->bf16, 1 bias+relu->bf16, 2 bias+residual (atomic if SPLITK>1).
// ---------------------------------------------------------------------------
template<int EPI, int SPLITK>
__global__ __launch_bounds__(512, 2)
void gemm256(const u16* __restrict__ A, const u16* __restrict__ BT,
             const float* __restrict__ bias,
             u16* __restrict__ Cb, float* __restrict__ Cf,
             int M, int N, int K) {
  __shared__ u16 lds[65536];                 // 128 KiB: A[2][256][64] | B[2][256][64]
  char* ldsb = (char*)lds;
  const int tid = threadIdx.x;
  const int lane = tid & 63;
  const int wid = tid >> 6;
  const int wm = wid >> 2, wn = wid & 3;
  const int l16 = lane & 15, lhi = lane >> 4;
  const int xr = (l16 & 7) << 4;             // read-side swizzle (row&7)<<4

  const int ntn = N >> 8;
  const int ntiles = (M >> 8) * ntn;
  const int nwg = ntiles * SPLITK;
  int wg = (int)blockIdx.x;
  if ((nwg & 7) == 0) { const int q = nwg >> 3; wg = (wg & 7) * q + (wg >> 3); }
  const int ks = wg / ntiles;
  const int tile = wg % ntiles;
  const int tm = tile / ntn, tn = tile % ntn;
  const int KS = K / SPLITK;
  const int k0 = ks * KS;
  const int NT = KS >> 6;                    // >= 16 for all uses here

  // staging source precompute: dest D = tid*16 + g*8192 (linear), source is
  // the inverse-swizzled global element so that swizzled reads see G[r][c].
  const u16 *aS[4], *bS[4];
  #pragma unroll
  for (int g = 0; g < 4; g++) {
    const int D  = tid * 16 + g * 8192;
    const int Dh = D & 16383, half = D >> 14;
    const int Ds = Dh ^ (((Dh >> 7) & 7) << 4);
    const int grow = half * 128 + (Ds >> 7);
    const int gcol = (Ds & 127) >> 1;
    aS[g] = A  + (size_t)(tm * 256 + grow) * K + k0 + gcol;
    bS[g] = BT + (size_t)(tn * 256 + grow) * K + k0 + gcol;
  }
  auto stageA = [&](int buf, int t) {
    #pragma unroll
    for (int g = 0; g < 4; g++)
      async16(ldsb + buf * 32768 + g * 8192 + tid * 16, aS[g] + t * 64);
  };
  auto stageB = [&](int buf, int t) {
    #pragma unroll
    for (int g = 0; g < 4; g++)
      async16(ldsb + 65536 + buf * 32768 + g * 8192 + tid * 16, bS[g] + t * 64);
  };
  // frag reads (swizzled)
  auto ldA = [&](int buf, int mq, int m, int kk) -> bf16x8 {
    const int L = (mq * 64 + m * 16 + l16) * 128 + kk * 64 + lhi * 16;
    return *(const bf16x8*)(ldsb + buf * 32768 + wm * 16384 + (L ^ xr));
  };
  auto ldB = [&](int buf, int nq, int n, int kk) -> bf16x8 {
    const int L = ((wn & 1) * 64 + nq * 32 + n * 16 + l16) * 128 + kk * 64 + lhi * 16;
    return *(const bf16x8*)(ldsb + 65536 + buf * 32768 + (wn >> 1) * 16384 + (L ^ xr));
  };

  f32x4 acc[8][4];
  #pragma unroll
  for (int m = 0; m < 8; m++)
    #pragma unroll
    for (int n = 0; n < 4; n++)
      #pragma unroll
      for (int j = 0; j < 4; j++) acc[m][n][j] = 0.0f;

  // prologue: tiles 0,1 in flight; gate tile0 (8 newest = tile1's loads)
  stageA(0, 0); stageB(0, 0);
  stageA(1, 1); stageB(1, 1);
  asm volatile("s_waitcnt vmcnt(8)" ::: "memory");
  BARRIER();

  bf16x8 a[4][2], b0[2][2], b1[2][2];
  for (int t = 0; t < NT; ++t) {
    const int buf = t & 1;
    // ---- p0: read A quarter mq0 + B half n01; MFMA q(0,0)
    #pragma unroll
    for (int m = 0; m < 4; m++)
      #pragma unroll
      for (int kk = 0; kk < 2; kk++) a[m][kk] = ldA(buf, 0, m, kk);
    #pragma unroll
    for (int n = 0; n < 2; n++)
      #pragma unroll
      for (int kk = 0; kk < 2; kk++) b0[n][kk] = ldB(buf, 0, n, kk);
    BARRIER();
    asm volatile("s_waitcnt lgkmcnt(0)" ::: "memory");
    __builtin_amdgcn_s_setprio(1);
    #pragma unroll
    for (int m = 0; m < 4; m++)
      #pragma unroll
      for (int n = 0; n < 2; n++)
        #pragma unroll
        for (int kk = 0; kk < 2; kk++)
          acc[m][n] = __builtin_amdgcn_mfma_f32_16x16x32_bf16(a[m][kk], b0[n][kk], acc[m][n], 0, 0, 0);
    __builtin_amdgcn_s_setprio(0);
    BARRIER();
    // ---- p1: read B half n23; MFMA q(0,1)
    #pragma unroll
    for (int n = 0; n < 2; n++)
      #pragma unroll
      for (int kk = 0; kk < 2; kk++) b1[n][kk] = ldB(buf, 1, n, kk);
    BARRIER();
    asm volatile("s_waitcnt lgkmcnt(0)" ::: "memory");
    __builtin_amdgcn_s_setprio(1);
    #pragma unroll
    for (int m = 0; m < 4; m++)
      #pragma unroll
      for (int n = 0; n < 2; n++)
        #pragma unroll
        for (int kk = 0; kk < 2; kk++)
          acc[m][2 + n] = __builtin_amdgcn_mfma_f32_16x16x32_bf16(a[m][kk], b1[n][kk], acc[m][2 + n], 0, 0, 0);
    __builtin_amdgcn_s_setprio(0);
    BARRIER();
    // ---- p2: read A quarter mq1; issue stage B(t+2) (B bufs free since p1);
    //          MFMA q(1,1)
    #pragma unroll
    for (int m = 0; m < 4; m++)
      #pragma unroll
      for (int kk = 0; kk < 2; kk++) a[m][kk] = ldA(buf, 1, m, kk);
    if (t + 2 < NT) stageB(buf, t + 2);
    BARRIER();
    asm volatile("s_waitcnt lgkmcnt(0)" ::: "memory");
    __builtin_amdgcn_s_setprio(1);
    #pragma unroll
    for (int m = 0; m < 4; m++)
      #pragma unroll
      for (int n = 0; n < 2; n++)
        #pragma unroll
        for (int kk = 0; kk < 2; kk++)
          acc[4 + m][2 + n] = __builtin_amdgcn_mfma_f32_16x16x32_bf16(a[m][kk], b1[n][kk], acc[4 + m][2 + n], 0, 0, 0);
    __builtin_amdgcn_s_setprio(0);
    BARRIER();
    // ---- p3: issue stage A(t+2) (A bufs free since p2); MFMA q(1,0)
    if (t + 2 < NT) stageA(buf, t + 2);
    BARRIER();
    __builtin_amdgcn_s_setprio(1);
    #pragma unroll
    for (int m = 0; m < 4; m++)
      #pragma unroll
      for (int n = 0; n < 2; n++)
        #pragma unroll
        for (int kk = 0; kk < 2; kk++)
          acc[4 + m][n] = __builtin_amdgcn_mfma_f32_16x16x32_bf16(a[m][kk], b0[n][kk], acc[4 + m][n], 0, 0, 0);
    __builtin_amdgcn_s_setprio(0);
    // ---- K-tile boundary gate: tile t+1's 8 loads must have landed;
    //      keep t+2's 8 (just issued) in flight.
    if (t + 1 < NT) {
      if (t + 2 < NT) asm volatile("s_waitcnt vmcnt(8)" ::: "memory");
      else            asm volatile("s_waitcnt vmcnt(0)" ::: "memory");
      BARRIER();
    }
  }

  // epilogue
  const int row0 = tm * 256 + wm * 128 + lhi * 4;
  const int col0 = tn * 256 + wn * 64 + l16;
  #pragma unroll
  for (int ng = 0; ng < 4; ng++) {
    const int col = col0 + ng * 16;
    const float bv = bias[col];
    #pragma unroll
    for (int mg = 0; mg < 8; mg++) {
      #pragma unroll
      for (int j = 0; j < 4; j++) {
        const int row = row0 + mg * 16 + j;
        float v = acc[mg][ng][j];
        if constexpr (EPI == 2 && SPLITK > 1) {
          if (ks == 0) v += bv;
          unsafeAtomicAdd(&Cf[(size_t)row * N + col], v);
        } else {
          v += bv;
          if constexpr (EPI == 1) v = fmaxf(v, 0.0f);
          if constexpr (EPI <= 1) Cb[(size_t)row * N + col] = f2bf(v);
          else                    Cf[(size_t)row * N + col] += v;
        }
      }
    }
  }
}

// ---------------------------------------------------------------------------
// GEMM (2-phase dbuf, 128xBN) — kept for wo (N=1024, K=1024, grid 512).
// ---------------------------------------------------------------------------
template<int EPI, int BN>
__global__ __launch_bounds__(256)
void gemm_bt(const u16* __restrict__ A, const u16* __restrict__ BT,
             const float* __restrict__ bias,
             u16* __restrict__ Cb, float* __restrict__ Cf,
             int M, int N, int K) {
  constexpr int WCn = BN / 64;
  constexpr int WR  = 4 / WCn;
  constexpr int MF  = 8 / WR;
  constexpr int WRS = 128 / WR;
  constexpr int ASZ = 128 * 32;
  constexpr int BSZ = BN * 32;
  __shared__ u16 As[2 * ASZ];
  __shared__ u16 Bs[2 * BSZ];
  const int tid = threadIdx.x;
  const int lane = tid & 63, wave = tid >> 6;
  const int wr = wave / WCn, wc = wave % WCn;
  const int l16 = lane & 15, lhi = lane >> 4;

  const int ntn = N / BN;
  const int nwg = (M >> 7) * ntn;
  int wg = (int)blockIdx.x;
  if ((nwg & 7) == 0) { const int q = nwg >> 3; wg = (wg & 7) * q + (wg >> 3); }
  const int tm = wg / ntn, tn = wg % ntn;

  const int srow = tid >> 2, sc = (tid & 3) * 8;
  const u16* Ag0 = A  + (size_t)(tm * 128 + srow) * K + sc;
  const u16* Bg0 = BT + (size_t)(tn * BN + srow) * K + sc;
  const size_t rstep = (size_t)64 * K;

  auto stage = [&](int buf, int k0) {
    async16(As + buf * ASZ + tid * 8, Ag0 + k0);
    async16(As + buf * ASZ + 2048 + tid * 8, Ag0 + rstep + k0);
    async16(Bs + buf * BSZ + tid * 8, Bg0 + k0);
    if constexpr (BN == 128) async16(Bs + buf * BSZ + 2048 + tid * 8, Bg0 + rstep + k0);
  };

  f32x4 acc[MF][4];
  #pragma unroll
  for (int m = 0; m < MF; m++)
    #pragma unroll
    for (int n = 0; n < 4; n++)
      #pragma unroll
      for (int j = 0; j < 4; j++) acc[m][n][j] = 0.0f;

  stage(0, 0);
  __syncthreads();
  int cur = 0;
  for (int k0 = 0; k0 < K; k0 += 32) {
    if (k0 + 32 < K) stage(cur ^ 1, k0 + 32);
    const u16* Ab = As + cur * ASZ;
    const u16* Bb = Bs + cur * BSZ;
    bf16x8 af[MF], bfv[4];
    #pragma unroll
    for (int m = 0; m < MF; m++)
      af[m] = *(const bf16x8*)&Ab[(wr * WRS + m * 16 + l16) * 32 + lhi * 8];
    #pragma unroll
    for (int n = 0; n < 4; n++)
      bfv[n] = *(const bf16x8*)&Bb[(wc * 64 + n * 16 + l16) * 32 + lhi * 8];
    #pragma unroll
    for (int m = 0; m < MF; m++)
      #pragma unroll
      for (int n = 0; n < 4; n++)
        acc[m][n] = __builtin_amdgcn_mfma_f32_16x16x32_bf16(af[m], bfv[n], acc[m][n], 0, 0, 0);
    __syncthreads();
    cur ^= 1;
  }

  const int row0 = tm * 128 + wr * WRS + lhi * 4;
  const int col0 = tn * BN + wc * 64 + l16;
  #pragma unroll
  for (int n = 0; n < 4; n++) {
    const int col = col0 + n * 16;
    const float bv = bias[col];
    #pragma unroll
    for (int m = 0; m < MF; m++) {
      #pragma unroll
      for (int j = 0; j < 4; j++) {
        const int row = row0 + m * 16 + j;
        float v = acc[m][n][j] + bv;
        if constexpr (EPI == 1) v = fmaxf(v, 0.0f);
        if constexpr (EPI <= 1) Cb[(size_t)row * N + col] = f2bf(v);
        else                    Cf[(size_t)row * N + col] += v;
      }
    }
  }
}

// ---------------------------------------------------------------------------
// Flash attention (unchanged from round 5)
// ---------------------------------------------------------------------------
__global__ __launch_bounds__(256, 4)
void attn(const u16* __restrict__ QKV, const u16* __restrict__ VTg,
          u16* __restrict__ Octx,
          const int* __restrict__ mask, const int* __restrict__ flags) {
  __shared__ u16 Ks[2 * 64 * 64];
  __shared__ u16 VTs[2 * 64 * 64];
  __shared__ u16 Ps[4 * 16 * 64];
  const int tid = threadIdx.x, lane = tid & 63, wv = tid >> 6;
  const int l16 = lane & 15, lhi = lane >> 4;
  const int bid = blockIdx.x;
  const int pair = bid >> 4, qblk = bid & 15;
  const int b = pair >> 4, h = pair & 15;
  const int hoff = h * DH;
  const int q0 = qblk * 64 + wv * 16;
  const size_t tokbase = (size_t)b * SEQ;
  const size_t vbase = ((size_t)b * 1024 + hoff) * SEQ;

  bf16x8 qf[2];
  #pragma unroll
  for (int ds = 0; ds < 2; ds++)
    qf[ds] = *(const bf16x8*)&QKV[(tokbase + q0 + l16) * QKVLD + hoff + ds * 32 + lhi * 8];

  f32x4 oacc[4];
  #pragma unroll
  for (int nt = 0; nt < 4; nt++)
    #pragma unroll
    for (int j = 0; j < 4; j++) oacc[nt][j] = 0.0f;
  float mrun = -1e30f, lrun = 0.0f;

  const int allone = flags[b];
  char* PwB = (char*)(Ps + wv * (16 * 64));
  const int xw = (l16 & 7) << 4;

  const int srow0 = tid >> 3, scb0 = (tid & 7) ^ (srow0 & 7);
  const int srow1 = (tid + 256) >> 3, scb1 = (tid & 7) ^ (srow1 & 7);
  const int shfl_src = (lane & 48) + ((lane >> 4) << 2);

  auto stage = [&](int buf, int kt) {
    async16((char*)Ks + buf * 8192 + tid * 16,
            &QKV[(tokbase + kt + srow0) * QKVLD + 1024 + hoff + scb0 * 8]);
    async16((char*)Ks + buf * 8192 + 4096 + tid * 16,
            &QKV[(tokbase + kt + srow1) * QKVLD + 1024 + hoff + scb1 * 8]);
    async16((char*)VTs + buf * 8192 + tid * 16,
            &VTg[vbase + (size_t)srow0 * SEQ + kt + scb0 * 8]);
    async16((char*)VTs + buf * 8192 + 4096 + tid * 16,
            &VTg[vbase + (size_t)srow1 * SEQ + kt + scb1 * 8]);
  };

  stage(0, 0);
  __syncthreads();
  int cur = 0;
  for (int kt = 0; kt < SEQ; kt += 64) {
    if (kt + 64 < SEQ) stage(cur ^ 1, kt + 64);
    char* KsB = (char*)Ks + cur * 8192;
    char* VTB = (char*)VTs + cur * 8192;

    f32x4 sacc[4];
    #pragma unroll
    for (int nt = 0; nt < 4; nt++)
      #pragma unroll
      for (int j = 0; j < 4; j++) sacc[nt][j] = 0.0f;
    #pragma unroll
    for (int ds = 0; ds < 2; ds++) {
      bf16x8 kf[4];
      #pragma unroll
      for (int nt = 0; nt < 4; nt++) {
        const int rk = nt * 16 + l16;
        kf[nt] = *(const bf16x8*)(KsB + ((rk * 128 + ds * 64 + lhi * 16) ^ ((rk & 7) << 4)));
      }
      #pragma unroll
      for (int nt = 0; nt < 4; nt++)
        sacc[nt] = __builtin_amdgcn_mfma_f32_16x16x32_bf16(kf[nt], qf[ds], sacc[nt], 0, 0, 0);
    }
    #pragma unroll
    for (int nt = 0; nt < 4; nt++)
      #pragma unroll
      for (int j = 0; j < 4; j++) sacc[nt][j] *= 0.125f;

    if (!allone) {
      const int qg = q0 + l16;
      #pragma unroll
      for (int nt = 0; nt < 4; nt++)
        #pragma unroll
        for (int j = 0; j < 4; j++) {
          const int kc = kt + nt * 16 + lhi * 4 + j;
          if (mask[(tokbase + qg) * SEQ + kc] == 0) sacc[nt][j] = -1e9f;
        }
    }

    float tmax = -1e30f;
    #pragma unroll
    for (int nt = 0; nt < 4; nt++)
      #pragma unroll
      for (int j = 0; j < 4; j++) tmax = fmaxf(tmax, sacc[nt][j]);
    tmax = fmaxf(tmax, __shfl_xor(tmax, 16));
    tmax = fmaxf(tmax, __shfl_xor(tmax, 32));
    const float mnew = fmaxf(mrun, tmax);
    const float corr = __expf(mrun - mnew);
    float p[4][4];
    float tsum = 0.0f;
    #pragma unroll
    for (int nt = 0; nt < 4; nt++)
      #pragma unroll
      for (int j = 0; j < 4; j++) { p[nt][j] = __expf(sacc[nt][j] - mnew); tsum += p[nt][j]; }
    tsum += __shfl_xor(tsum, 16);
    tsum += __shfl_xor(tsum, 32);
    lrun = lrun * corr + tsum;
    mrun = mnew;

    #pragma unroll
    for (int nt = 0; nt < 4; nt++) {
      const uint32_t lo = (uint32_t)f2bf(p[nt][0]) | ((uint32_t)f2bf(p[nt][1]) << 16);
      const uint32_t hi = (uint32_t)f2bf(p[nt][2]) | ((uint32_t)f2bf(p[nt][3]) << 16);
      *(uint64_t*)(PwB + ((l16 * 128 + nt * 32 + lhi * 8) ^ xw)) =
          (uint64_t)lo | ((uint64_t)hi << 32);
    }

    float cj[4];
    #pragma unroll
    for (int j = 0; j < 4; j++) cj[j] = __shfl(corr, shfl_src + j);
    #pragma unroll
    for (int nt = 0; nt < 4; nt++)
      #pragma unroll
      for (int j = 0; j < 4; j++) oacc[nt][j] *= cj[j];

    #pragma unroll
    for (int ksl = 0; ksl < 2; ksl++) {
      const bf16x8 pf = *(const bf16x8*)(PwB + ((l16 * 128 + ksl * 64 + lhi * 16) ^ xw));
      #pragma unroll
      for (int nt = 0; nt < 4; nt++) {
        const int dr = nt * 16 + l16;
        const bf16x8 vf = *(const bf16x8*)(VTB + ((dr * 128 + ksl * 64 + lhi * 16) ^ ((dr & 7) << 4)));
        oacc[nt] = __builtin_amdgcn_mfma_f32_16x16x32_bf16(pf, vf, oacc[nt], 0, 0, 0);
      }
    }
    __syncthreads();
    cur ^= 1;
  }

  const float linv = 1.0f / lrun;
  float lj[4];
  #pragma unroll
  for (int j = 0; j < 4; j++) lj[j] = __shfl(linv, shfl_src + j);
  #pragma unroll
  for (int j = 0; j < 4; j++) {
    const size_t rowg = (tokbase + q0 + lhi * 4 + j) * DM + hoff;
    #pragma unroll
    for (int nt = 0; nt < 4; nt++)
      Octx[rowg + nt * 16 + l16] = f2bf(oacc[nt][j] * lj[j]);
  }
}

// ---------------------------------------------------------------------------
// Orchestration
// ---------------------------------------------------------------------------
extern "C" void kernel_launch(void* const* d_in, const int* in_sizes, int n_in,
                              void* d_out, int out_size, void* d_ws, size_t ws_size,
                              hipStream_t stream) {
  const float* x    = (const float*)d_in[0];
  const int*   mask = (const int*)d_in[1];
  const float* wq = (const float*)d_in[2];
  const float* bq = (const float*)d_in[3];
  const float* wk = (const float*)d_in[4];
  const float* bk = (const float*)d_in[5];
  const float* wvp = (const float*)d_in[6];
  const float* bv = (const float*)d_in[7];
  const float* wo = (const float*)d_in[8];
  const float* bo = (const float*)d_in[9];
  const float* w1 = (const float*)d_in[10];
  const float* b1 = (const float*)d_in[11];
  const float* w2 = (const float*)d_in[12];
  const float* b2 = (const float*)d_in[13];
  const float* ln1g = (const float*)d_in[14];
  const float* ln1b = (const float*)d_in[15];
  const float* ln2g = (const float*)d_in[16];
  const float* ln2b = (const float*)d_in[17];
  const float* lnfg = (const float*)d_in[18];
  const float* lnfb = (const float*)d_in[19];

  char* ws = (char*)d_ws;
  float* xbuf = (float*)(ws);                        // 16 MB f32 residual
  u16* xn1  = (u16*)(ws + ((size_t)16 << 20));       // 8 MB
  u16* xn2  = (u16*)(ws + ((size_t)24 << 20));       // 8 MB
  u16* qkv  = (u16*)(ws + ((size_t)32 << 20));       // 24 MB [tok][3072]
  u16* ctx  = (u16*)(ws + ((size_t)56 << 20));       // 8 MB
  u16* hb   = (u16*)(ws + ((size_t)32 << 20));       // 32 MB alias (qkv+ctx dead by FFN)
  u16* wqkvT= (u16*)(ws + ((size_t)64 << 20));       // 6 MB [3072][1024]
  u16* woT  = (u16*)(ws + ((size_t)70 << 20));       // 2 MB
  u16* w1T  = (u16*)(ws + ((size_t)72 << 20));       // 8 MB
  u16* w2T  = (u16*)(ws + ((size_t)80 << 20));       // 8 MB
  u16* vT   = (u16*)(ws + ((size_t)88 << 20));       // 8 MB [(b*1024+hd)][s]
  float* bqkv = (float*)(ws + ((size_t)96 << 20));   // 12 KB
  int* flags  = (int*)(ws + ((size_t)96 << 20) + 65536);

  hipMemcpyAsync(xbuf, x, (size_t)NTOK * DM * sizeof(float),
                 hipMemcpyDeviceToDevice, stream);
  flags_init<<<1, 64, 0, stream>>>(flags);
  mask_flags<<<1024, 256, 0, stream>>>(mask, flags);

  auto wgs64 = [](int M, int N) { return dim3((unsigned)((M >> 7) * (N >> 6))); };

  for (int i = 0; i < DEPTH; i++) {
    prep<<<12300, 256, 0, stream>>>(
        wq  + (size_t)i * DM * DM,  wk + (size_t)i * DM * DM,
        wvp + (size_t)i * DM * DM,  wo + (size_t)i * DM * DM,
        w1  + (size_t)i * DM * DFF, w2 + (size_t)i * DFF * DM,
        bq + i * DM, bk + i * DM, bv + i * DM,
        wqkvT, woT, w1T, w2T, bqkv);

    ln_dual<<<NTOK, 256, 0, stream>>>(xbuf, ln1g + i * DM, ln1b + i * DM,
                                      ln2g + i * DM, ln2b + i * DM, xn1, xn2);

    // QKV: 256^2 tiles -> grid 192
    gemm256<0, 1><<<dim3(192), 512, 0, stream>>>(xn1, wqkvT, bqkv, qkv, nullptr,
                                                 NTOK, QKVLD, DM);
    vtrans<<<dim3(16, 16, 4), 256, 0, stream>>>(qkv, vT);

    attn<<<1024, 256, 0, stream>>>(qkv, vT, ctx, mask, flags);

    gemm_bt<2, 64><<<wgs64(NTOK, DM), 256, 0, stream>>>(ctx, woT, bo + i * DM, nullptr, xbuf,
                                                        NTOK, DM, DM);
    // w1: 256^2 tiles -> grid 256
    gemm256<1, 1><<<dim3(256), 512, 0, stream>>>(xn2, w1T, b1 + i * DFF, hb, nullptr,
                                                 NTOK, DFF, DM);
    // w2: 256^2 tiles x split-K=4 -> grid 256, atomic f32 accumulate into xbuf
    gemm256<2, 4><<<dim3(256), 512, 0, stream>>>(hb, w2T, b2 + i * DM, nullptr, xbuf,
                                                 NTOK, DM, DFF);
  }

  ln_final<<<NTOK, 256, 0, stream>>>(xbuf, lnfg, lnfb, (float*)d_out);
}

// Round 7
// 1517.975 us; speedup vs baseline: 1.0481x; 1.0481x over previous
//
#include <hip/hip_runtime.h>
#include <hip/hip_bf16.h>
#include <stdint.h>

#define DEPTH 6
#define DM 1024
#define DFF 4096
#define NH 16
#define DH 64
#define BATCH 4
#define SEQ 1024
#define NTOK (BATCH*SEQ)
#define QKVLD 3072

using bf16x8 = __attribute__((ext_vector_type(8))) short;
using f32x4  = __attribute__((ext_vector_type(4))) float;
typedef unsigned short u16;

__device__ __forceinline__ u16 f2bf(float f) {
  union { float f; uint32_t u; } v; v.f = f;
  return (u16)((v.u + 0x7FFFu + ((v.u >> 16) & 1u)) >> 16);
}

// async global->LDS, 16B per lane. LDS dest must be wave-uniform base + lane*16.
__device__ __forceinline__ void async16(void* lds, const void* g) {
  __builtin_amdgcn_global_load_lds(
      (__attribute__((address_space(1))) void*)(unsigned long long)g,
      (__attribute__((address_space(3))) void*)(unsigned int)(unsigned long long)lds,
      16, 0, 0);
}

// ---------------------------------------------------------------------------
// prep: ALL weight conversions for one layer in ONE dispatch.
// ---------------------------------------------------------------------------
__global__ __launch_bounds__(256)
void prep(const float* __restrict__ wq, const float* __restrict__ wk,
          const float* __restrict__ wv, const float* __restrict__ wo,
          const float* __restrict__ w1, const float* __restrict__ w2,
          const float* __restrict__ bq, const float* __restrict__ bk,
          const float* __restrict__ bv,
          u16* __restrict__ wqkvT, u16* __restrict__ woT,
          u16* __restrict__ w1T, u16* __restrict__ w2T,
          float* __restrict__ bqkv) {
  const int bid = blockIdx.x;
  if (bid >= 12288) {
    const int t = (bid - 12288) * 256 + threadIdx.x;  // 0..3071
    bqkv[t] = t < 1024 ? bq[t] : (t < 2048 ? bk[t - 1024] : bv[t - 2048]);
    return;
  }
  const float* w; u16* wt; int K, N, tile;
  if (bid < 3072)      { const int r = bid >> 10;
                         w = r == 0 ? wq : (r == 1 ? wk : wv);
                         wt = wqkvT + (size_t)r * 1024 * 1024; K = 1024; N = 1024; tile = bid & 1023; }
  else if (bid < 4096) { w = wo; wt = woT; K = 1024; N = 1024; tile = bid - 3072; }
  else if (bid < 8192) { w = w1; wt = w1T; K = 1024; N = 4096; tile = bid - 4096; }
  else                 { w = w2; wt = w2T; K = 4096; N = 1024; tile = bid - 8192; }
  const int ntn = N >> 5;
  const int k0 = (tile / ntn) << 5, n0 = (tile % ntn) << 5;

  __shared__ u16 t[32][33];
  const int tx = threadIdx.x & 31, ty = threadIdx.x >> 5;
  #pragma unroll
  for (int r = ty; r < 32; r += 8)
    t[r][tx] = f2bf(w[(size_t)(k0 + r) * N + n0 + tx]);
  __syncthreads();
  #pragma unroll
  for (int r = ty; r < 32; r += 8)
    wt[(size_t)(n0 + r) * K + k0 + tx] = t[tx][r];
}

// ---------------------------------------------------------------------------
// V-transpose: qkv[tok][3072] section 2048.. -> vt[(b*1024+hd)][s]  (bf16)
// ---------------------------------------------------------------------------
__global__ __launch_bounds__(256)
void vtrans(const u16* __restrict__ qkv, u16* __restrict__ vt) {
  __shared__ u16 t[64][72];
  const int s0 = blockIdx.x * 64, c0 = blockIdx.y * 64, b = blockIdx.z;
  const int r = threadIdx.x >> 2, cq = threadIdx.x & 3;
  const u16* src = qkv + ((size_t)(b * SEQ + s0 + r)) * QKVLD + 2048 + c0 + cq * 16;
  *(bf16x8*)&t[r][cq * 16]     = *(const bf16x8*)(src);
  *(bf16x8*)&t[r][cq * 16 + 8] = *(const bf16x8*)(src + 8);
  __syncthreads();
  bf16x8 a, bvec;
  #pragma unroll
  for (int i = 0; i < 8; i++) a[i] = (short)t[cq * 16 + i][r];
  #pragma unroll
  for (int i = 0; i < 8; i++) bvec[i] = (short)t[cq * 16 + 8 + i][r];
  u16* dst = vt + ((size_t)(b * 1024 + c0 + r)) * SEQ + s0 + cq * 16;
  *(bf16x8*)dst = a;
  *(bf16x8*)(dst + 8) = bvec;
}

// ---------------------------------------------------------------------------
// Mask all-ones flags (per batch)
// ---------------------------------------------------------------------------
__global__ void flags_init(int* flags) {
  if (threadIdx.x < BATCH) flags[threadIdx.x] = 1;
}
__global__ void mask_flags(const int* __restrict__ mask, int* __restrict__ flags) {
  const size_t n = (size_t)BATCH * SEQ * SEQ;
  for (size_t i = (size_t)blockIdx.x * 256 + threadIdx.x; i < n; i += (size_t)gridDim.x * 256)
    if (mask[i] == 0) flags[i / ((size_t)SEQ * SEQ)] = 0;
}

// ---------------------------------------------------------------------------
// Dual LayerNorm: x f32 (+ optional w2 partial slab fold, written back) -> bf16
// ---------------------------------------------------------------------------
__global__ __launch_bounds__(256)
void ln_dual(float* __restrict__ x, const float* __restrict__ slab,
             const float* __restrict__ g1, const float* __restrict__ b1v,
             const float* __restrict__ g2, const float* __restrict__ b2v,
             u16* __restrict__ o1, u16* __restrict__ o2) {
  const int row = blockIdx.x, tid = threadIdx.x;
  float4 v = ((const float4*)(x + (size_t)row * DM))[tid];
  if (slab) {
    const float4 sv = ((const float4*)(slab + (size_t)row * DM))[tid];
    v.x += sv.x; v.y += sv.y; v.z += sv.z; v.w += sv.w;
    ((float4*)(x + (size_t)row * DM))[tid] = v;   // persist folded residual
  }
  float s = v.x + v.y + v.z + v.w;
  float sq = v.x*v.x + v.y*v.y + v.z*v.z + v.w*v.w;
  #pragma unroll
  for (int o = 32; o; o >>= 1) { s += __shfl_xor(s, o); sq += __shfl_xor(sq, o); }
  __shared__ float red[8];
  const int lane = tid & 63, w = tid >> 6;
  if (lane == 0) { red[w] = s; red[4 + w] = sq; }
  __syncthreads();
  s = red[0] + red[1] + red[2] + red[3];
  sq = red[4] + red[5] + red[6] + red[7];
  const float mean = s * (1.0f / DM);
  const float rinv = rsqrtf(sq * (1.0f / DM) - mean * mean + 1e-5f);
  const float4 G1 = ((const float4*)g1)[tid], B1 = ((const float4*)b1v)[tid];
  const float4 G2 = ((const float4*)g2)[tid], B2 = ((const float4*)b2v)[tid];
  const float n0 = (v.x - mean) * rinv, n1 = (v.y - mean) * rinv;
  const float n2 = (v.z - mean) * rinv, n3 = (v.w - mean) * rinv;
  ushort4 a, bb;
  a.x = f2bf(n0*G1.x + B1.x); a.y = f2bf(n1*G1.y + B1.y);
  a.z = f2bf(n2*G1.z + B1.z); a.w = f2bf(n3*G1.w + B1.w);
  bb.x = f2bf(n0*G2.x + B2.x); bb.y = f2bf(n1*G2.y + B2.y);
  bb.z = f2bf(n2*G2.z + B2.z); bb.w = f2bf(n3*G2.w + B2.w);
  ((ushort4*)(o1 + (size_t)row * DM))[tid] = a;
  ((ushort4*)(o2 + (size_t)row * DM))[tid] = bb;
}

__global__ __launch_bounds__(256)
void ln_final(const float* __restrict__ x, const float* __restrict__ slab,
              const float* __restrict__ g, const float* __restrict__ b,
              float* __restrict__ out) {
  const int row = blockIdx.x, tid = threadIdx.x;
  float4 v = ((const float4*)(x + (size_t)row * DM))[tid];
  if (slab) {
    const float4 sv = ((const float4*)(slab + (size_t)row * DM))[tid];
    v.x += sv.x; v.y += sv.y; v.z += sv.z; v.w += sv.w;
  }
  float s = v.x + v.y + v.z + v.w;
  float sq = v.x*v.x + v.y*v.y + v.z*v.z + v.w*v.w;
  #pragma unroll
  for (int o = 32; o; o >>= 1) { s += __shfl_xor(s, o); sq += __shfl_xor(sq, o); }
  __shared__ float red[8];
  const int lane = tid & 63, w = tid >> 6;
  if (lane == 0) { red[w] = s; red[4 + w] = sq; }
  __syncthreads();
  s = red[0] + red[1] + red[2] + red[3];
  sq = red[4] + red[5] + red[6] + red[7];
  const float mean = s * (1.0f / DM);
  const float rinv = rsqrtf(sq * (1.0f / DM) - mean * mean + 1e-5f);
  const float4 G = ((const float4*)g)[tid], B = ((const float4*)b)[tid];
  float4 o;
  o.x = (v.x - mean) * rinv * G.x + B.x;
  o.y = (v.y - mean) * rinv * G.y + B.y;
  o.z = (v.z - mean) * rinv * G.z + B.z;
  o.w = (v.w - mean) * rinv * G.w + B.w;
  ((float4*)(out + (size_t)row * DM))[tid] = o;
}

// ---------------------------------------------------------------------------
// GEMM: C[M,N] = A[M,K](bf16) * BT[N,K]^T(bf16) + bias.
// 2-phase double-buffered LDS. BM=128; BN in {128,64}; optional split-K.
// EPI: 0 bias->bf16, 1 bias+relu->bf16, 2 bias+residual '+=' f32,
//      3 split-K: ks=0 '+= bias+acc' into Cf (sole writer), ks=1 plain store
//        of acc into Cf2 slab (folded later by ln_dual/ln_final).
// ---------------------------------------------------------------------------
template<int EPI, int BN, int SPLITK>
__global__ __launch_bounds__(256)
void gemm_bt(const u16* __restrict__ A, const u16* __restrict__ BT,
             const float* __restrict__ bias,
             u16* __restrict__ Cb, float* __restrict__ Cf, float* __restrict__ Cf2,
             int M, int N, int K) {
  constexpr int WCn = BN / 64;
  constexpr int WR  = 4 / WCn;
  constexpr int MF  = 8 / WR;
  constexpr int WRS = 128 / WR;
  constexpr int ASZ = 128 * 32;
  constexpr int BSZ = BN * 32;
  __shared__ u16 As[2 * ASZ];
  __shared__ u16 Bs[2 * BSZ];
  const int tid = threadIdx.x;
  const int lane = tid & 63, wave = tid >> 6;
  const int wr = wave / WCn, wc = wave % WCn;
  const int l16 = lane & 15, lhi = lane >> 4;

  const int ntn = N / BN;
  const int ntiles = (M >> 7) * ntn;
  const int nwg = ntiles * SPLITK;
  int wg = (int)blockIdx.x;
  if ((nwg & 7) == 0) { const int q = nwg >> 3; wg = (wg & 7) * q + (wg >> 3); }
  const int tile = wg / SPLITK, ks = wg % SPLITK;
  const int tm = tile / ntn, tn = tile % ntn;
  const int KL = K / SPLITK;

  const int srow = tid >> 2, sc = (tid & 3) * 8;
  const u16* Ag0 = A  + (size_t)(tm * 128 + srow) * K + ks * KL + sc;
  const u16* Bg0 = BT + (size_t)(tn * BN + srow) * K + ks * KL + sc;
  const size_t rstep = (size_t)64 * K;

  auto stage = [&](int buf, int k0) {
    async16(As + buf * ASZ + tid * 8, Ag0 + k0);
    async16(As + buf * ASZ + 2048 + tid * 8, Ag0 + rstep + k0);
    async16(Bs + buf * BSZ + tid * 8, Bg0 + k0);
    if constexpr (BN == 128) async16(Bs + buf * BSZ + 2048 + tid * 8, Bg0 + rstep + k0);
  };

  f32x4 acc[MF][4];
  #pragma unroll
  for (int m = 0; m < MF; m++)
    #pragma unroll
    for (int n = 0; n < 4; n++)
      #pragma unroll
      for (int j = 0; j < 4; j++) acc[m][n][j] = 0.0f;

  stage(0, 0);
  __syncthreads();
  int cur = 0;
  for (int k0 = 0; k0 < KL; k0 += 32) {
    if (k0 + 32 < KL) stage(cur ^ 1, k0 + 32);
    const u16* Ab = As + cur * ASZ;
    const u16* Bb = Bs + cur * BSZ;
    bf16x8 af[MF], bfv[4];
    #pragma unroll
    for (int m = 0; m < MF; m++)
      af[m] = *(const bf16x8*)&Ab[(wr * WRS + m * 16 + l16) * 32 + lhi * 8];
    #pragma unroll
    for (int n = 0; n < 4; n++)
      bfv[n] = *(const bf16x8*)&Bb[(wc * 64 + n * 16 + l16) * 32 + lhi * 8];
    #pragma unroll
    for (int m = 0; m < MF; m++)
      #pragma unroll
      for (int n = 0; n < 4; n++)
        acc[m][n] = __builtin_amdgcn_mfma_f32_16x16x32_bf16(af[m], bfv[n], acc[m][n], 0, 0, 0);
    __syncthreads();
    cur ^= 1;
  }

  const int row0 = tm * 128 + wr * WRS + lhi * 4;
  const int col0 = tn * BN + wc * 64 + l16;
  #pragma unroll
  for (int n = 0; n < 4; n++) {
    const int col = col0 + n * 16;
    const float bv = bias[col];
    #pragma unroll
    for (int m = 0; m < MF; m++) {
      #pragma unroll
      for (int j = 0; j < 4; j++) {
        const int row = row0 + m * 16 + j;
        const size_t idx = (size_t)row * N + col;
        float v = acc[m][n][j];
        if constexpr (EPI == 3) {
          if (ks == 0) Cf[idx] += v + bv;   // sole RMW writer for this element
          else         Cf2[idx] = v;        // plain slab store, folded later
        } else {
          v += bv;
          if constexpr (EPI == 1) v = fmaxf(v, 0.0f);
          if constexpr (EPI <= 1) Cb[idx] = f2bf(v);
          else                    Cf[idx] += v;
        }
      }
    }
  }
}

// ---------------------------------------------------------------------------
// Flash attention (unchanged from round 5)
// ---------------------------------------------------------------------------
__global__ __launch_bounds__(256, 4)
void attn(const u16* __restrict__ QKV, const u16* __restrict__ VTg,
          u16* __restrict__ Octx,
          const int* __restrict__ mask, const int* __restrict__ flags) {
  __shared__ u16 Ks[2 * 64 * 64];
  __shared__ u16 VTs[2 * 64 * 64];
  __shared__ u16 Ps[4 * 16 * 64];
  const int tid = threadIdx.x, lane = tid & 63, wv = tid >> 6;
  const int l16 = lane & 15, lhi = lane >> 4;
  const int bid = blockIdx.x;
  const int pair = bid >> 4, qblk = bid & 15;
  const int b = pair >> 4, h = pair & 15;
  const int hoff = h * DH;
  const int q0 = qblk * 64 + wv * 16;
  const size_t tokbase = (size_t)b * SEQ;
  const size_t vbase = ((size_t)b * 1024 + hoff) * SEQ;

  bf16x8 qf[2];
  #pragma unroll
  for (int ds = 0; ds < 2; ds++)
    qf[ds] = *(const bf16x8*)&QKV[(tokbase + q0 + l16) * QKVLD + hoff + ds * 32 + lhi * 8];

  f32x4 oacc[4];
  #pragma unroll
  for (int nt = 0; nt < 4; nt++)
    #pragma unroll
    for (int j = 0; j < 4; j++) oacc[nt][j] = 0.0f;
  float mrun = -1e30f, lrun = 0.0f;

  const int allone = flags[b];
  char* PwB = (char*)(Ps + wv * (16 * 64));
  const int xw = (l16 & 7) << 4;

  const int srow0 = tid >> 3, scb0 = (tid & 7) ^ (srow0 & 7);
  const int srow1 = (tid + 256) >> 3, scb1 = (tid & 7) ^ (srow1 & 7);
  const int shfl_src = (lane & 48) + ((lane >> 4) << 2);

  auto stage = [&](int buf, int kt) {
    async16((char*)Ks + buf * 8192 + tid * 16,
            &QKV[(tokbase + kt + srow0) * QKVLD + 1024 + hoff + scb0 * 8]);
    async16((char*)Ks + buf * 8192 + 4096 + tid * 16,
            &QKV[(tokbase + kt + srow1) * QKVLD + 1024 + hoff + scb1 * 8]);
    async16((char*)VTs + buf * 8192 + tid * 16,
            &VTg[vbase + (size_t)srow0 * SEQ + kt + scb0 * 8]);
    async16((char*)VTs + buf * 8192 + 4096 + tid * 16,
            &VTg[vbase + (size_t)srow1 * SEQ + kt + scb1 * 8]);
  };

  stage(0, 0);
  __syncthreads();
  int cur = 0;
  for (int kt = 0; kt < SEQ; kt += 64) {
    if (kt + 64 < SEQ) stage(cur ^ 1, kt + 64);
    char* KsB = (char*)Ks + cur * 8192;
    char* VTB = (char*)VTs + cur * 8192;

    f32x4 sacc[4];
    #pragma unroll
    for (int nt = 0; nt < 4; nt++)
      #pragma unroll
      for (int j = 0; j < 4; j++) sacc[nt][j] = 0.0f;
    #pragma unroll
    for (int ds = 0; ds < 2; ds++) {
      bf16x8 kf[4];
      #pragma unroll
      for (int nt = 0; nt < 4; nt++) {
        const int rk = nt * 16 + l16;
        kf[nt] = *(const bf16x8*)(KsB + ((rk * 128 + ds * 64 + lhi * 16) ^ ((rk & 7) << 4)));
      }
      #pragma unroll
      for (int nt = 0; nt < 4; nt++)
        sacc[nt] = __builtin_amdgcn_mfma_f32_16x16x32_bf16(kf[nt], qf[ds], sacc[nt], 0, 0, 0);
    }
    #pragma unroll
    for (int nt = 0; nt < 4; nt++)
      #pragma unroll
      for (int j = 0; j < 4; j++) sacc[nt][j] *= 0.125f;

    if (!allone) {
      const int qg = q0 + l16;
      #pragma unroll
      for (int nt = 0; nt < 4; nt++)
        #pragma unroll
        for (int j = 0; j < 4; j++) {
          const int kc = kt + nt * 16 + lhi * 4 + j;
          if (mask[(tokbase + qg) * SEQ + kc] == 0) sacc[nt][j] = -1e9f;
        }
    }

    float tmax = -1e30f;
    #pragma unroll
    for (int nt = 0; nt < 4; nt++)
      #pragma unroll
      for (int j = 0; j < 4; j++) tmax = fmaxf(tmax, sacc[nt][j]);
    tmax = fmaxf(tmax, __shfl_xor(tmax, 16));
    tmax = fmaxf(tmax, __shfl_xor(tmax, 32));
    const float mnew = fmaxf(mrun, tmax);
    const float corr = __expf(mrun - mnew);
    float p[4][4];
    float tsum = 0.0f;
    #pragma unroll
    for (int nt = 0; nt < 4; nt++)
      #pragma unroll
      for (int j = 0; j < 4; j++) { p[nt][j] = __expf(sacc[nt][j] - mnew); tsum += p[nt][j]; }
    tsum += __shfl_xor(tsum, 16);
    tsum += __shfl_xor(tsum, 32);
    lrun = lrun * corr + tsum;
    mrun = mnew;

    #pragma unroll
    for (int nt = 0; nt < 4; nt++) {
      const uint32_t lo = (uint32_t)f2bf(p[nt][0]) | ((uint32_t)f2bf(p[nt][1]) << 16);
      const uint32_t hi = (uint32_t)f2bf(p[nt][2]) | ((uint32_t)f2bf(p[nt][3]) << 16);
      *(uint64_t*)(PwB + ((l16 * 128 + nt * 32 + lhi * 8) ^ xw)) =
          (uint64_t)lo | ((uint64_t)hi << 32);
    }

    float cj[4];
    #pragma unroll
    for (int j = 0; j < 4; j++) cj[j] = __shfl(corr, shfl_src + j);
    #pragma unroll
    for (int nt = 0; nt < 4; nt++)
      #pragma unroll
      for (int j = 0; j < 4; j++) oacc[nt][j] *= cj[j];

    #pragma unroll
    for (int ksl = 0; ksl < 2; ksl++) {
      const bf16x8 pf = *(const bf16x8*)(PwB + ((l16 * 128 + ksl * 64 + lhi * 16) ^ xw));
      #pragma unroll
      for (int nt = 0; nt < 4; nt++) {
        const int dr = nt * 16 + l16;
        const bf16x8 vf = *(const bf16x8*)(VTB + ((dr * 128 + ksl * 64 + lhi * 16) ^ ((dr & 7) << 4)));
        oacc[nt] = __builtin_amdgcn_mfma_f32_16x16x32_bf16(pf, vf, oacc[nt], 0, 0, 0);
      }
    }
    __syncthreads();
    cur ^= 1;
  }

  const float linv = 1.0f / lrun;
  float lj[4];
  #pragma unroll
  for (int j = 0; j < 4; j++) lj[j] = __shfl(linv, shfl_src + j);
  #pragma unroll
  for (int j = 0; j < 4; j++) {
    const size_t rowg = (tokbase + q0 + lhi * 4 + j) * DM + hoff;
    #pragma unroll
    for (int nt = 0; nt < 4; nt++)
      Octx[rowg + nt * 16 + l16] = f2bf(oacc[nt][j] * lj[j]);
  }
}

// ---------------------------------------------------------------------------
// Orchestration
// ---------------------------------------------------------------------------
extern "C" void kernel_launch(void* const* d_in, const int* in_sizes, int n_in,
                              void* d_out, int out_size, void* d_ws, size_t ws_size,
                              hipStream_t stream) {
  const float* x    = (const float*)d_in[0];
  const int*   mask = (const int*)d_in[1];
  const float* wq = (const float*)d_in[2];
  const float* bq = (const float*)d_in[3];
  const float* wk = (const float*)d_in[4];
  const float* bk = (const float*)d_in[5];
  const float* wvp = (const float*)d_in[6];
  const float* bv = (const float*)d_in[7];
  const float* wo = (const float*)d_in[8];
  const float* bo = (const float*)d_in[9];
  const float* w1 = (const float*)d_in[10];
  const float* b1 = (const float*)d_in[11];
  const float* w2 = (const float*)d_in[12];
  const float* b2 = (const float*)d_in[13];
  const float* ln1g = (const float*)d_in[14];
  const float* ln1b = (const float*)d_in[15];
  const float* ln2g = (const float*)d_in[16];
  const float* ln2b = (const float*)d_in[17];
  const float* lnfg = (const float*)d_in[18];
  const float* lnfb = (const float*)d_in[19];

  char* ws = (char*)d_ws;
  float* xbuf = (float*)(ws);                        // 16 MB f32 residual
  u16* xn1  = (u16*)(ws + ((size_t)16 << 20));       // 8 MB
  u16* xn2  = (u16*)(ws + ((size_t)24 << 20));       // 8 MB
  u16* qkv  = (u16*)(ws + ((size_t)32 << 20));       // 24 MB [tok][3072]
  u16* ctx  = (u16*)(ws + ((size_t)56 << 20));       // 8 MB
  u16* hb   = (u16*)(ws + ((size_t)32 << 20));       // 32 MB alias (qkv+ctx dead by FFN)
  u16* wqkvT= (u16*)(ws + ((size_t)64 << 20));       // 6 MB [3072][1024]
  u16* woT  = (u16*)(ws + ((size_t)70 << 20));       // 2 MB
  u16* w1T  = (u16*)(ws + ((size_t)72 << 20));       // 8 MB
  u16* w2T  = (u16*)(ws + ((size_t)80 << 20));       // 8 MB
  u16* vT   = (u16*)(ws + ((size_t)88 << 20));       // 8 MB [(b*1024+hd)][s]
  float* bqkv = (float*)(ws + ((size_t)96 << 20));   // 12 KB
  int* flags  = (int*)(ws + ((size_t)96 << 20) + 65536);
  float* slab = (float*)(ws + ((size_t)97 << 20));   // 16 MB w2 ks=1 partials

  // split-K for w2 needs the 16 MB slab at 97..113 MB
  const bool splitw2 = ws_size >= ((size_t)113 << 20);

  hipMemcpyAsync(xbuf, x, (size_t)NTOK * DM * sizeof(float),
                 hipMemcpyDeviceToDevice, stream);
  flags_init<<<1, 64, 0, stream>>>(flags);
  mask_flags<<<1024, 256, 0, stream>>>(mask, flags);

  auto wgs128 = [](int M, int N) { return dim3((unsigned)((M >> 7) * (N >> 7))); };
  auto wgs64  = [](int M, int N) { return dim3((unsigned)((M >> 7) * (N >> 6))); };

  for (int i = 0; i < DEPTH; i++) {
    prep<<<12300, 256, 0, stream>>>(
        wq  + (size_t)i * DM * DM,  wk + (size_t)i * DM * DM,
        wvp + (size_t)i * DM * DM,  wo + (size_t)i * DM * DM,
        w1  + (size_t)i * DM * DFF, w2 + (size_t)i * DFF * DM,
        bq + i * DM, bk + i * DM, bv + i * DM,
        wqkvT, woT, w1T, w2T, bqkv);

    // folds previous layer's w2 slab into the residual stream (and persists it)
    ln_dual<<<NTOK, 256, 0, stream>>>(xbuf, (splitw2 && i > 0) ? slab : nullptr,
                                      ln1g + i * DM, ln1b + i * DM,
                                      ln2g + i * DM, ln2b + i * DM, xn1, xn2);

    gemm_bt<0, 128, 1><<<wgs128(NTOK, QKVLD), 256, 0, stream>>>(
        xn1, wqkvT, bqkv, qkv, nullptr, nullptr, NTOK, QKVLD, DM);
    vtrans<<<dim3(16, 16, 4), 256, 0, stream>>>(qkv, vT);

    attn<<<1024, 256, 0, stream>>>(qkv, vT, ctx, mask, flags);

    gemm_bt<2, 64, 1><<<wgs64(NTOK, DM), 256, 0, stream>>>(
        ctx, woT, bo + i * DM, nullptr, xbuf, nullptr, NTOK, DM, DM);
    gemm_bt<1, 128, 1><<<wgs128(NTOK, DFF), 256, 0, stream>>>(
        xn2, w1T, b1 + i * DFF, hb, nullptr, nullptr, NTOK, DFF, DM);

    if (splitw2) {
      // split-K=2: grid 1024 = 4 blocks/CU (m114: the 2-phase structure needs
      // ~4/CU of inter-block overlap). ks=0 RMWs xbuf (+bias), ks=1 -> slab.
      gemm_bt<3, 64, 2><<<dim3((NTOK >> 7) * (DM >> 6) * 2), 256, 0, stream>>>(
          hb, w2T, b2 + i * DM, nullptr, xbuf, slab, NTOK, DM, DFF);
    } else {
      gemm_bt<2, 64, 1><<<wgs64(NTOK, DM), 256, 0, stream>>>(
          hb, w2T, b2 + i * DM, nullptr, xbuf, nullptr, NTOK, DM, DFF);
    }
  }

  ln_final<<<NTOK, 256, 0, stream>>>(xbuf, splitw2 ? slab : nullptr,
                                     lnfg, lnfb, (float*)d_out);
}